// Round 1
// baseline (1655.076 us; speedup 1.0000x reference)
//
#include <hip/hip_runtime.h>

#define E_EXP 8
#define D_IN 1024
#define D_H 4096
#define D_OUT 1024
#define N_TOK 4096

using f32x4  = __attribute__((ext_vector_type(4))) float;
using bf16x8 = __attribute__((ext_vector_type(8))) __bf16;

typedef __attribute__((address_space(1))) void gvoid_t;
typedef __attribute__((address_space(3))) void lvoid_t;

// async global->LDS, 16B per lane; LDS dest is wave-uniform base + lane*16
__device__ __forceinline__ void async_load16(const void* g, void* l) {
    __builtin_amdgcn_global_load_lds((gvoid_t*)g, (lvoid_t*)l, 16, 0, 0);
}

__device__ __forceinline__ unsigned short f2bf(float f) {
    unsigned int x = __float_as_uint(f);
    x += 0x7fffu + ((x >> 16) & 1u);   // round-to-nearest-even
    return (unsigned short)(x >> 16);
}

// ---------------- cast x fp32 -> bf16 ----------------
__global__ __launch_bounds__(256) void cast_x_kernel(const float* __restrict__ in,
                                                     unsigned short* __restrict__ outp) {
    int i = blockIdx.x * 256 + threadIdx.x;
    float4 f = ((const float4*)in)[i];
    ushort4 u;
    u.x = f2bf(f.x); u.y = f2bf(f.y); u.z = f2bf(f.z); u.w = f2bf(f.w);
    ((ushort4*)outp)[i] = u;
}

// ---------------- gate: softmax(x @ Wg + bg) over E=8, fp32 ----------------
__global__ __launch_bounds__(256) void gate_kernel(const float* __restrict__ x,
                                                   const float* __restrict__ Wg,
                                                   const float* __restrict__ bg,
                                                   float* __restrict__ gate) {
    int wave = threadIdx.x >> 6, lane = threadIdx.x & 63;
    int n = blockIdx.x * 4 + wave;
    int e = lane & 7, part = lane >> 3;                 // 8 experts x 8 K-parts
    const float* xr = x + (size_t)n * D_IN + part * (D_IN / 8);
    const float* wr = Wg + (size_t)part * (D_IN / 8) * E_EXP + e;
    float s = 0.f;
#pragma unroll 4
    for (int d = 0; d < D_IN / 8; d++) s += xr[d] * wr[d * E_EXP];
    s += __shfl_xor(s, 8);
    s += __shfl_xor(s, 16);
    s += __shfl_xor(s, 32);                              // full dot per expert
    s += bg[e];
    float m = s;
    m = fmaxf(m, __shfl_xor(m, 1));
    m = fmaxf(m, __shfl_xor(m, 2));
    m = fmaxf(m, __shfl_xor(m, 4));
    float ex = __expf(s - m);
    float sum = ex;
    sum += __shfl_xor(sum, 1);
    sum += __shfl_xor(sum, 2);
    sum += __shfl_xor(sum, 4);
    if (lane < 8) gate[n * 8 + lane] = ex / sum;
}

// ---------------- transpose+cast: in fp32 [z][R][C] -> out bf16 [z][C][R] ----------------
__global__ __launch_bounds__(256) void transpose_cast(const float* __restrict__ in,
                                                      unsigned short* __restrict__ outp,
                                                      int R, int C) {
    in   += (size_t)blockIdx.z * R * C;
    outp += (size_t)blockIdx.z * R * C;
    __shared__ float tile[32][33];
    int x = threadIdx.x & 31, y = threadIdx.x >> 5;
    int r0 = blockIdx.y * 32, c0 = blockIdx.x * 32;
#pragma unroll
    for (int i = 0; i < 32; i += 8)
        tile[y + i][x] = in[(size_t)(r0 + y + i) * C + c0 + x];
    __syncthreads();
#pragma unroll
    for (int i = 0; i < 32; i += 8) {
        int c = y + i;
        outp[(size_t)(c0 + c) * R + r0 + x] = f2bf(tile[x][c]);
    }
}

// ---------------- bf16 MFMA GEMM, 128x128 tile, BK=32, m97-style staging ----------------
// A: [M][K] bf16 row-major (k-contig). B: [Nmat][K] bf16 n-major (k-contig) == Bmat^T.
// MODE 0: H[row][col] = bf16(relu(acc + bias[col]))         (layer 1)
// MODE 1: out[row][col] (=|+=) gateE[row*8] * (acc + bias[col])   (layer 2 + combine)
template <int MODE>
__global__ __launch_bounds__(256) void gemm_kernel(const unsigned short* __restrict__ A,
                                                   const unsigned short* __restrict__ B,
                                                   const float* __restrict__ bias,
                                                   const float* __restrict__ gateE,
                                                   unsigned short* __restrict__ H,
                                                   float* __restrict__ out,
                                                   int K, int N, int first) {
    __shared__ __align__(16) unsigned short As[128 * 32];
    __shared__ __align__(16) unsigned short Bs[128 * 32];
    const int t = threadIdx.x;
    const int wave = t >> 6;
    const int lane = t & 63;
    const int quad = lane >> 4;
    const int l16 = lane & 15;
    const int m0 = blockIdx.y * 128;
    const int n0 = blockIdx.x * 128;
    const int wm = (wave & 1) * 64;
    const int wn = (wave >> 1) * 64;

    // staging: 512 chunks of 16B per tile; thread t does chunks t and t+256.
    // LDS layout = unpadded row-major [128][32] bf16 (64B/row, 4 chunks/row).
    const int c0 = t, c1 = t + 256;
    const unsigned short* a0 = A + (size_t)(m0 + (c0 >> 2)) * K + (c0 & 3) * 8;
    const unsigned short* a1 = A + (size_t)(m0 + (c1 >> 2)) * K + (c1 & 3) * 8;
    const unsigned short* b0 = B + (size_t)(n0 + (c0 >> 2)) * K + (c0 & 3) * 8;
    const unsigned short* b1 = B + (size_t)(n0 + (c1 >> 2)) * K + (c1 & 3) * 8;
    unsigned short* lA0 = &As[wave * 512];          // wave-uniform LDS bases
    unsigned short* lA1 = &As[2048 + wave * 512];
    unsigned short* lB0 = &Bs[wave * 512];
    unsigned short* lB1 = &Bs[2048 + wave * 512];

    f32x4 acc[4][4] = {};

    for (int k = 0; k < K; k += 32) {
        async_load16(a0 + k, lA0);
        async_load16(a1 + k, lA1);
        async_load16(b0 + k, lB0);
        async_load16(b1 + k, lB1);
        __syncthreads();
        bf16x8 af[4], bf[4];
#pragma unroll
        for (int i = 0; i < 4; i++)
            af[i] = *reinterpret_cast<const bf16x8*>(&As[(wm + i * 16 + l16) * 32 + quad * 8]);
#pragma unroll
        for (int j = 0; j < 4; j++)
            bf[j] = *reinterpret_cast<const bf16x8*>(&Bs[(wn + j * 16 + l16) * 32 + quad * 8]);
#pragma unroll
        for (int i = 0; i < 4; i++)
#pragma unroll
            for (int j = 0; j < 4; j++)
                acc[i][j] = __builtin_amdgcn_mfma_f32_16x16x32_bf16(af[i], bf[j], acc[i][j], 0, 0, 0);
        __syncthreads();
    }

    // C/D layout: col = lane&15, row = quad*4 + reg   [verified m89/m91]
    const int mrow = m0 + wm + quad * 4;
    const int ncol = n0 + wn + l16;
    if (MODE == 0) {
#pragma unroll
        for (int i = 0; i < 4; i++) {
#pragma unroll
            for (int r = 0; r < 4; r++) {
                int row = mrow + i * 16 + r;
                unsigned short* hr = H + (size_t)row * N;
#pragma unroll
                for (int j = 0; j < 4; j++) {
                    int col = ncol + j * 16;
                    float v = acc[i][j][r] + bias[col];
                    hr[col] = f2bf(fmaxf(v, 0.f));
                }
            }
        }
    } else {
#pragma unroll
        for (int i = 0; i < 4; i++) {
#pragma unroll
            for (int r = 0; r < 4; r++) {
                int row = mrow + i * 16 + r;
                float g = gateE[row * 8];
                float* orow = out + (size_t)row * N;
#pragma unroll
                for (int j = 0; j < 4; j++) {
                    int col = ncol + j * 16;
                    float v = g * (acc[i][j][r] + bias[col]);
                    if (first) orow[col] = v;
                    else       orow[col] += v;
                }
            }
        }
    }
}

extern "C" void kernel_launch(void* const* d_in, const int* in_sizes, int n_in,
                              void* d_out, int out_size, void* d_ws, size_t ws_size,
                              hipStream_t stream) {
    const float* x  = (const float*)d_in[0];
    const float* W1 = (const float*)d_in[1];
    const float* b1 = (const float*)d_in[2];
    const float* W2 = (const float*)d_in[3];
    const float* b2 = (const float*)d_in[4];
    const float* Wg = (const float*)d_in[5];
    const float* bg = (const float*)d_in[6];
    float* out = (float*)d_out;

    // workspace layout (~168 MiB total)
    char* p = (char*)d_ws;
    unsigned short* xb  = (unsigned short*)p; p += (size_t)N_TOK * D_IN * 2;        //  8 MiB
    unsigned short* W1T = (unsigned short*)p; p += (size_t)E_EXP * D_IN * D_H * 2;  // 64 MiB [e][h][k]
    unsigned short* W2T = (unsigned short*)p; p += (size_t)E_EXP * D_H * D_OUT * 2; // 64 MiB [e][o][h]
    unsigned short* h   = (unsigned short*)p; p += (size_t)N_TOK * D_H * 2;         // 32 MiB (per-expert, reused)
    float* gate         = (float*)p;                                                // 128 KiB

    cast_x_kernel<<<dim3(N_TOK * D_IN / 1024), 256, 0, stream>>>(x, xb);
    gate_kernel<<<dim3(N_TOK / 4), 256, 0, stream>>>(x, Wg, bg, gate);
    // W1 [e][1024][4096] -> W1T [e][4096][1024]
    transpose_cast<<<dim3(D_H / 32, D_IN / 32, E_EXP), 256, 0, stream>>>(W1, W1T, D_IN, D_H);
    // W2 [e][4096][1024] -> W2T [e][1024][4096]
    transpose_cast<<<dim3(D_OUT / 32, D_H / 32, E_EXP), 256, 0, stream>>>(W2, W2T, D_H, D_OUT);

    for (int e = 0; e < E_EXP; e++) {
        gemm_kernel<0><<<dim3(D_H / 128, N_TOK / 128), 256, 0, stream>>>(
            xb, W1T + (size_t)e * D_IN * D_H, b1 + (size_t)e * D_H,
            nullptr, h, nullptr, D_IN, D_H, 0);
        gemm_kernel<1><<<dim3(D_OUT / 128, N_TOK / 128), 256, 0, stream>>>(
            h, W2T + (size_t)e * D_H * D_OUT, b2 + (size_t)e * D_OUT,
            gate + e, nullptr, out, D_H, D_OUT, e == 0);
    }
}

// Round 2
// 1276.448 us; speedup vs baseline: 1.2966x; 1.2966x over previous
//
#include <hip/hip_runtime.h>

#define E_EXP 8
#define D_IN 1024
#define D_H 4096
#define D_OUT 1024
#define N_TOK 4096

using f32x4  = __attribute__((ext_vector_type(4))) float;
using bf16x8 = __attribute__((ext_vector_type(8))) __bf16;

typedef __attribute__((address_space(1))) void gvoid_t;
typedef __attribute__((address_space(3))) void lvoid_t;

// async global->LDS, 16B per lane; LDS dest is wave-uniform base + lane*16
__device__ __forceinline__ void async_load16(const void* g, void* l) {
    __builtin_amdgcn_global_load_lds((gvoid_t*)g, (lvoid_t*)l, 16, 0, 0);
}

__device__ __forceinline__ unsigned short f2bf(float f) {
    unsigned int x = __float_as_uint(f);
    x += 0x7fffu + ((x >> 16) & 1u);   // round-to-nearest-even
    return (unsigned short)(x >> 16);
}

// ---------------- cast x fp32 -> bf16 ----------------
__global__ __launch_bounds__(256) void cast_x_kernel(const float* __restrict__ in,
                                                     unsigned short* __restrict__ outp) {
    int i = blockIdx.x * 256 + threadIdx.x;
    float4 f = ((const float4*)in)[i];
    ushort4 u;
    u.x = f2bf(f.x); u.y = f2bf(f.y); u.z = f2bf(f.z); u.w = f2bf(f.w);
    ((ushort4*)outp)[i] = u;
}

// ---------------- gate: softmax(x @ Wg + bg) over E=8, fp32 ----------------
__global__ __launch_bounds__(256) void gate_kernel(const float* __restrict__ x,
                                                   const float* __restrict__ Wg,
                                                   const float* __restrict__ bg,
                                                   float* __restrict__ gate) {
    int wave = threadIdx.x >> 6, lane = threadIdx.x & 63;
    int n = blockIdx.x * 4 + wave;
    int e = lane & 7, part = lane >> 3;                 // 8 experts x 8 K-parts
    const float* xr = x + (size_t)n * D_IN + part * (D_IN / 8);
    const float* wr = Wg + (size_t)part * (D_IN / 8) * E_EXP + e;
    float s = 0.f;
#pragma unroll 4
    for (int d = 0; d < D_IN / 8; d++) s += xr[d] * wr[d * E_EXP];
    s += __shfl_xor(s, 8);
    s += __shfl_xor(s, 16);
    s += __shfl_xor(s, 32);                              // full dot per expert
    s += bg[e];
    float m = s;
    m = fmaxf(m, __shfl_xor(m, 1));
    m = fmaxf(m, __shfl_xor(m, 2));
    m = fmaxf(m, __shfl_xor(m, 4));
    float ex = __expf(s - m);
    float sum = ex;
    sum += __shfl_xor(sum, 1);
    sum += __shfl_xor(sum, 2);
    sum += __shfl_xor(sum, 4);
    if (lane < 8) gate[n * 8 + lane] = ex / sum;
}

// ---------------- transpose+cast: in fp32 [z][R][C] -> out bf16 [z][C][R] ----------------
__global__ __launch_bounds__(256) void transpose_cast(const float* __restrict__ in,
                                                      unsigned short* __restrict__ outp,
                                                      int R, int C) {
    in   += (size_t)blockIdx.z * R * C;
    outp += (size_t)blockIdx.z * R * C;
    __shared__ float tile[32][33];
    int x = threadIdx.x & 31, y = threadIdx.x >> 5;
    int r0 = blockIdx.y * 32, c0 = blockIdx.x * 32;
#pragma unroll
    for (int i = 0; i < 32; i += 8)
        tile[y + i][x] = in[(size_t)(r0 + y + i) * C + c0 + x];
    __syncthreads();
#pragma unroll
    for (int i = 0; i < 32; i += 8) {
        int c = y + i;
        outp[(size_t)(c0 + c) * R + r0 + x] = f2bf(tile[x][c]);
    }
}

// ---------------- out init: out[n][o] = sum_e gate[n,e]*b2[e,o] ----------------
__global__ __launch_bounds__(256) void out_init_kernel(const float* __restrict__ gate,
                                                       const float* __restrict__ b2,
                                                       float* __restrict__ out) {
    int i = blockIdx.x * 256 + threadIdx.x;          // one float4 of out
    int n = i / (D_OUT / 4), o4 = i % (D_OUT / 4);
    const float* g = gate + n * 8;
    float4 s = make_float4(0.f, 0.f, 0.f, 0.f);
#pragma unroll
    for (int e = 0; e < E_EXP; e++) {
        float4 b = ((const float4*)(b2 + (size_t)e * D_OUT))[o4];
        float ge = g[e];
        s.x += ge * b.x; s.y += ge * b.y; s.z += ge * b.z; s.w += ge * b.w;
    }
    ((float4*)out)[i] = s;
}

// ---------------- bf16 MFMA GEMM, 128x128 tile, BK=32, swizzled LDS ----------------
// MODE 0 (layer1): A=xb [N_TOK][D_IN], B=W1T[e][h][k]; writes
//                  Hout[er*h_estride + row*D_H + col] = bf16(gate[row,e]*relu(acc+b1[e,col]))
// MODE 1 (layer2): A=h'+er*h_estride [N_TOK][D_H], B=W2T[e][o][h];
//                  atomicAdd(out[row*D_OUT+col], acc). z encodes (er,kz): er=z/kzc, kz=z%kzc.
template <int MODE>
__global__ __launch_bounds__(256) void gemm_kernel(const unsigned short* __restrict__ Abase,
                                                   const unsigned short* __restrict__ Wbase,
                                                   const float* __restrict__ b1a,
                                                   const float* __restrict__ gate,
                                                   unsigned short* __restrict__ Hout,
                                                   float* __restrict__ out,
                                                   int e_off, int kzc, size_t h_estride) {
    __shared__ __align__(16) unsigned short As[128 * 32];
    __shared__ __align__(16) unsigned short Bs[128 * 32];
    const int t = threadIdx.x;
    const int wave = t >> 6;
    const int lane = t & 63;
    const int quad = lane >> 4;
    const int l16 = lane & 15;
    const int n0 = blockIdx.x * 128;        // col-tile (h for MODE0, o for MODE1)
    const int m0 = blockIdx.y * 128;        // token rows
    int er, kz;
    if (MODE == 0) { er = blockIdx.z; kz = 0; }
    else           { er = (int)(blockIdx.z) / kzc; kz = (int)(blockIdx.z) % kzc; }
    const int e = e_off + er;
    const int ld = (MODE == 0) ? D_IN : D_H;     // K-stride for both A and B
    const int Kc = ((MODE == 0) ? D_IN : D_H) / kzc;
    const int kbase = kz * Kc;

    const unsigned short* A = Abase + (MODE == 1 ? (size_t)er * h_estride : (size_t)0);
    const unsigned short* B = Wbase + (size_t)e * 4194304;   // 4M elems per expert slice

    // staging: 512 phys 16B-chunks per tile; thread t owns phys chunks t and t+256.
    // phys(row,q) = row*4 + ((q + (row>>1)) & 3)  -> gather global chunk accordingly.
    const int r0 = t >> 2,        q0 = ((t & 3) - (r0 >> 1)) & 3;
    const int p1 = t + 256;
    const int r1 = p1 >> 2,       q1 = ((p1 & 3) - (r1 >> 1)) & 3;
    const unsigned short* a0 = A + (size_t)(m0 + r0) * ld + kbase + q0 * 8;
    const unsigned short* a1 = A + (size_t)(m0 + r1) * ld + kbase + q1 * 8;
    const unsigned short* b0 = B + (size_t)(n0 + r0) * ld + kbase + q0 * 8;
    const unsigned short* b1p = B + (size_t)(n0 + r1) * ld + kbase + q1 * 8;
    unsigned short* lA0 = &As[wave * 512];          // wave-uniform LDS bases
    unsigned short* lA1 = &As[2048 + wave * 512];
    unsigned short* lB0 = &Bs[wave * 512];
    unsigned short* lB1 = &Bs[2048 + wave * 512];

    const int wm = (wave & 1) * 64;
    const int wn = (wave >> 1) * 64;
    f32x4 acc[4][4] = {};

    for (int k = 0; k < Kc; k += 32) {
        async_load16(a0 + k, lA0);
        async_load16(a1 + k, lA1);
        async_load16(b0 + k, lB0);
        async_load16(b1p + k, lB1);
        __syncthreads();
        bf16x8 af[4], bfr[4];
#pragma unroll
        for (int i = 0; i < 4; i++) {
            int row = wm + i * 16 + l16;
            af[i] = *reinterpret_cast<const bf16x8*>(&As[row * 32 + ((quad + (row >> 1)) & 3) * 8]);
        }
#pragma unroll
        for (int j = 0; j < 4; j++) {
            int row = wn + j * 16 + l16;
            bfr[j] = *reinterpret_cast<const bf16x8*>(&Bs[row * 32 + ((quad + (row >> 1)) & 3) * 8]);
        }
#pragma unroll
        for (int i = 0; i < 4; i++)
#pragma unroll
            for (int j = 0; j < 4; j++)
                acc[i][j] = __builtin_amdgcn_mfma_f32_16x16x32_bf16(af[i], bfr[j], acc[i][j], 0, 0, 0);
        __syncthreads();
    }

    // C/D layout: col = lane&15, row = quad*4 + reg   [verified m89/m91]
    const int mrow = m0 + wm + quad * 4;
    const int ncol = n0 + wn + l16;
    if (MODE == 0) {
        const float* bias = b1a + (size_t)e * D_H;
        unsigned short* Hbase = Hout + (size_t)er * h_estride;
#pragma unroll
        for (int i = 0; i < 4; i++) {
#pragma unroll
            for (int r = 0; r < 4; r++) {
                int row = mrow + i * 16 + r;
                float g = gate[row * 8 + e];
                unsigned short* hr = Hbase + (size_t)row * D_H;
#pragma unroll
                for (int j = 0; j < 4; j++) {
                    int col = ncol + j * 16;
                    float v = fmaxf(acc[i][j][r] + bias[col], 0.f) * g;
                    hr[col] = f2bf(v);
                }
            }
        }
    } else {
#pragma unroll
        for (int i = 0; i < 4; i++) {
#pragma unroll
            for (int r = 0; r < 4; r++) {
                int row = mrow + i * 16 + r;
                float* orow = out + (size_t)row * D_OUT;
#pragma unroll
                for (int j = 0; j < 4; j++) {
                    int col = ncol + j * 16;
                    unsafeAtomicAdd(&orow[col], acc[i][j][r]);
                }
            }
        }
    }
}

extern "C" void kernel_launch(void* const* d_in, const int* in_sizes, int n_in,
                              void* d_out, int out_size, void* d_ws, size_t ws_size,
                              hipStream_t stream) {
    const float* x  = (const float*)d_in[0];
    const float* W1 = (const float*)d_in[1];
    const float* b1 = (const float*)d_in[2];
    const float* W2 = (const float*)d_in[3];
    const float* b2 = (const float*)d_in[4];
    const float* Wg = (const float*)d_in[5];
    const float* bg = (const float*)d_in[6];
    float* out = (float*)d_out;

    // workspace layout
    char* p = (char*)d_ws;
    unsigned short* xb  = (unsigned short*)p; p += (size_t)N_TOK * D_IN * 2;        //   8 MiB
    unsigned short* W1T = (unsigned short*)p; p += (size_t)E_EXP * D_IN * D_H * 2;  //  64 MiB [e][h][k]
    unsigned short* W2T = (unsigned short*)p; p += (size_t)E_EXP * D_H * D_OUT * 2; //  64 MiB [e][o][h]
    float* gate         = (float*)p;          p += (size_t)N_TOK * E_EXP * 4;       // 128 KiB
    unsigned short* h   = (unsigned short*)p;                                       // fused: 256 MiB, fallback: 32 MiB

    const size_t fused_need = (size_t)N_TOK * D_IN * 2 + (size_t)E_EXP * D_IN * D_H * 2 +
                              (size_t)E_EXP * D_H * D_OUT * 2 + (size_t)N_TOK * E_EXP * 4 +
                              (size_t)E_EXP * N_TOK * D_H * 2;   // 411,172,864 B
    const bool fused = ws_size >= fused_need;

    cast_x_kernel<<<dim3(N_TOK * D_IN / 1024), 256, 0, stream>>>(x, xb);
    gate_kernel<<<dim3(N_TOK / 4), 256, 0, stream>>>(x, Wg, bg, gate);
    // W1 [e][1024][4096] -> W1T [e][4096][1024]
    transpose_cast<<<dim3(D_H / 32, D_IN / 32, E_EXP), 256, 0, stream>>>(W1, W1T, D_IN, D_H);
    // W2 [e][4096][1024] -> W2T [e][1024][4096]
    transpose_cast<<<dim3(D_OUT / 32, D_H / 32, E_EXP), 256, 0, stream>>>(W2, W2T, D_H, D_OUT);
    // out = sum_e gate*b2 (GEMM2 atomically accumulates on top)
    out_init_kernel<<<dim3(N_TOK * D_OUT / 1024), 256, 0, stream>>>(gate, b2, out);

    if (fused) {
        const size_t hstride = (size_t)N_TOK * D_H;
        gemm_kernel<0><<<dim3(D_H / 128, N_TOK / 128, E_EXP), 256, 0, stream>>>(
            xb, W1T, b1, gate, h, nullptr, 0, 1, hstride);
        gemm_kernel<1><<<dim3(D_OUT / 128, N_TOK / 128, E_EXP), 256, 0, stream>>>(
            h, W2T, nullptr, nullptr, nullptr, out, 0, 1, hstride);
    } else {
        for (int e = 0; e < E_EXP; e++) {
            gemm_kernel<0><<<dim3(D_H / 128, N_TOK / 128, 1), 256, 0, stream>>>(
                xb, W1T, b1, gate, h, nullptr, e, 1, 0);
            gemm_kernel<1><<<dim3(D_OUT / 128, N_TOK / 128, 4), 256, 0, stream>>>(
                h, W2T, nullptr, nullptr, nullptr, out, e, 4, 0);
        }
    }
}

// Round 3
// 1118.709 us; speedup vs baseline: 1.4795x; 1.1410x over previous
//
#include <hip/hip_runtime.h>

#define E_EXP 8
#define D_IN 1024
#define D_H 4096
#define D_OUT 1024
#define N_TOK 4096

using f32x4  = __attribute__((ext_vector_type(4))) float;
using bf16x8 = __attribute__((ext_vector_type(8))) __bf16;

typedef __attribute__((address_space(1))) void gvoid_t;
typedef __attribute__((address_space(3))) void lvoid_t;

// async global->LDS, 16B per lane; LDS dest is wave-uniform base + lane*16
__device__ __forceinline__ void async_load16(const void* g, void* l) {
    __builtin_amdgcn_global_load_lds((gvoid_t*)g, (lvoid_t*)l, 16, 0, 0);
}

__device__ __forceinline__ unsigned short f2bf(float f) {
    unsigned int x = __float_as_uint(f);
    x += 0x7fffu + ((x >> 16) & 1u);   // round-to-nearest-even
    return (unsigned short)(x >> 16);
}

// ---------------- cast x fp32 -> bf16 ----------------
__global__ __launch_bounds__(256) void cast_x_kernel(const float* __restrict__ in,
                                                     unsigned short* __restrict__ outp) {
    int i = blockIdx.x * 256 + threadIdx.x;
    float4 f = ((const float4*)in)[i];
    ushort4 u;
    u.x = f2bf(f.x); u.y = f2bf(f.y); u.z = f2bf(f.z); u.w = f2bf(f.w);
    ((ushort4*)outp)[i] = u;
}

// ---------------- gate: softmax(x @ Wg + bg) over E=8, fp32 ----------------
__global__ __launch_bounds__(256) void gate_kernel(const float* __restrict__ x,
                                                   const float* __restrict__ Wg,
                                                   const float* __restrict__ bg,
                                                   float* __restrict__ gate) {
    int wave = threadIdx.x >> 6, lane = threadIdx.x & 63;
    int n = blockIdx.x * 4 + wave;
    int e = lane & 7, part = lane >> 3;                 // 8 experts x 8 K-parts
    const float* xr = x + (size_t)n * D_IN + part * (D_IN / 8);
    const float* wr = Wg + (size_t)part * (D_IN / 8) * E_EXP + e;
    float s = 0.f;
#pragma unroll 4
    for (int d = 0; d < D_IN / 8; d++) s += xr[d] * wr[d * E_EXP];
    s += __shfl_xor(s, 8);
    s += __shfl_xor(s, 16);
    s += __shfl_xor(s, 32);                              // full dot per expert
    s += bg[e];
    float m = s;
    m = fmaxf(m, __shfl_xor(m, 1));
    m = fmaxf(m, __shfl_xor(m, 2));
    m = fmaxf(m, __shfl_xor(m, 4));
    float ex = __expf(s - m);
    float sum = ex;
    sum += __shfl_xor(sum, 1);
    sum += __shfl_xor(sum, 2);
    sum += __shfl_xor(sum, 4);
    if (lane < 8) gate[n * 8 + lane] = ex / sum;
}

// ---------------- transpose+cast: in fp32 [z][R][C] -> out bf16 [z][C][R] ----------------
__global__ __launch_bounds__(256) void transpose_cast(const float* __restrict__ in,
                                                      unsigned short* __restrict__ outp,
                                                      int R, int C) {
    in   += (size_t)blockIdx.z * R * C;
    outp += (size_t)blockIdx.z * R * C;
    __shared__ float tile[32][33];
    int x = threadIdx.x & 31, y = threadIdx.x >> 5;
    int r0 = blockIdx.y * 32, c0 = blockIdx.x * 32;
#pragma unroll
    for (int i = 0; i < 32; i += 8)
        tile[y + i][x] = in[(size_t)(r0 + y + i) * C + c0 + x];
    __syncthreads();
#pragma unroll
    for (int i = 0; i < 32; i += 8) {
        int c = y + i;
        outp[(size_t)(c0 + c) * R + r0 + x] = f2bf(tile[x][c]);
    }
}

// ---------------- out init: out[n][o] = sum_e gate[n,e]*b2[e,o] ----------------
__global__ __launch_bounds__(256) void out_init_kernel(const float* __restrict__ gate,
                                                       const float* __restrict__ b2,
                                                       float* __restrict__ out) {
    int i = blockIdx.x * 256 + threadIdx.x;          // one float4 of out
    int n = i / (D_OUT / 4), o4 = i % (D_OUT / 4);
    const float* g = gate + n * 8;
    float4 s = make_float4(0.f, 0.f, 0.f, 0.f);
#pragma unroll
    for (int e = 0; e < E_EXP; e++) {
        float4 b = ((const float4*)(b2 + (size_t)e * D_OUT))[o4];
        float ge = g[e];
        s.x += ge * b.x; s.y += ge * b.y; s.z += ge * b.z; s.w += ge * b.w;
    }
    ((float4*)out)[i] = s;
}

// ---------------- bf16 MFMA GEMM, 128x128 tile, BK=64, XCD-swizzled 1-D grid ----------------
// LDS tile: [128 rows][64 k] bf16, rows = 128 B = 8 chunks of 16 B.
// Swizzle: phys_chunk(row, c) = c ^ (row & 7)  -> ds_read_b128 conflict-free.
// MODE 0 (layer1): A=xb [N_TOK][D_IN], B=W1T[e][h][k], K=1024; writes
//                  h[er*hstride + row*D_H + col] = bf16(gate[row,e]*relu(acc + b1[e,col]))
// MODE 1 (layer2): A=h+er*hstride [N_TOK][D_H], B=W2T[e][o][h], K=4096;
//                  unsafeAtomicAdd(out[row*D_OUT + col], acc)
// Grid is 1-D; decode assigns each XCD (id&7) a fixed 4-m-tile slice, with the
// col-tile fastest (A-tile sharers co-XCD, adjacent) and expert slowest.
template <int MODE>
__global__ __launch_bounds__(256) void gemm_kernel(const unsigned short* __restrict__ Abase,
                                                   const unsigned short* __restrict__ Wbase,
                                                   const float* __restrict__ b1a,
                                                   const float* __restrict__ gate,
                                                   unsigned short* __restrict__ Hout,
                                                   float* __restrict__ out,
                                                   int e0, size_t hstride) {
    __shared__ __align__(16) unsigned short As[128 * 64];
    __shared__ __align__(16) unsigned short Bs[128 * 64];
    const int t = threadIdx.x;
    const int wave = t >> 6;
    const int lane = t & 63;
    const int quad = lane >> 4;
    const int l16 = lane & 15;

    const int lin = blockIdx.x;
    const int xcd = lin & 7;
    const int s = lin >> 3;
    int n_t, er, m_t;
    if (MODE == 0) {                 // 4096 blocks: s in [0,512)
        n_t = s & 31;                // 32 col-tiles (fastest: share A-tile)
        int em = s >> 5;             // [0,16)
        er = em >> 2;                // expert slowest -> B-tiles L2-resident
        m_t = (em & 3) + xcd * 4;
    } else {                         // 1024 blocks: s in [0,128)
        n_t = s & 7;                 // 8 col-tiles
        int em = s >> 3;             // [0,16)
        er = em >> 2;
        m_t = (em & 3) + xcd * 4;
    }
    const int e = e0 + er;
    const int n0 = n_t * 128;
    const int m0 = m_t * 128;
    const int ld = (MODE == 0) ? D_IN : D_H;
    const int K  = (MODE == 0) ? D_IN : D_H;

    const unsigned short* A = Abase + (MODE == 1 ? (size_t)er * hstride : (size_t)0);
    const unsigned short* B = Wbase + (size_t)e * 4194304;   // 4M elems per expert slice

    // staging: tile = 1024 chunks of 16 B; thread t owns phys chunks t+j*256, j=0..3.
    // phys p: row = p>>3, cph = p&7; fetch global logical chunk c = cph ^ (row&7).
    const int r0 = t >> 3;                       // row for j=0; row_j = r0 + j*32
    const int gk = ((t & 7) ^ (r0 & 7)) << 3;    // same for all j (32 % 8 == 0)
    const unsigned short* aP = A + (size_t)(m0 + r0) * ld + gk;
    const unsigned short* bP = B + (size_t)(n0 + r0) * ld + gk;

    const int wm = (wave & 1) * 64;
    const int wn = (wave >> 1) * 64;
    f32x4 acc[4][4] = {};

    for (int k = 0; k < K; k += 64) {
#pragma unroll
        for (int j = 0; j < 4; j++)
            async_load16(aP + k + (size_t)j * 32 * ld, &As[(j * 256 + wave * 64) * 8]);
#pragma unroll
        for (int j = 0; j < 4; j++)
            async_load16(bP + k + (size_t)j * 32 * ld, &Bs[(j * 256 + wave * 64) * 8]);
        __syncthreads();
#pragma unroll
        for (int half = 0; half < 2; half++) {
            bf16x8 af[4], bfr[4];
#pragma unroll
            for (int i = 0; i < 4; i++) {
                int row = wm + i * 16 + l16;
                af[i] = *reinterpret_cast<const bf16x8*>(
                    &As[row * 64 + (((half << 2) + quad) ^ (row & 7)) * 8]);
            }
#pragma unroll
            for (int j = 0; j < 4; j++) {
                int row = wn + j * 16 + l16;
                bfr[j] = *reinterpret_cast<const bf16x8*>(
                    &Bs[row * 64 + (((half << 2) + quad) ^ (row & 7)) * 8]);
            }
#pragma unroll
            for (int i = 0; i < 4; i++)
#pragma unroll
                for (int j = 0; j < 4; j++)
                    acc[i][j] = __builtin_amdgcn_mfma_f32_16x16x32_bf16(af[i], bfr[j], acc[i][j], 0, 0, 0);
        }
        __syncthreads();
    }

    // C/D layout: col = lane&15, row = quad*4 + reg   [verified m89/m91]
    const int mrow = m0 + wm + quad * 4;
    const int ncol = n0 + wn + l16;
    if (MODE == 0) {
        const float* bias = b1a + (size_t)e * D_H;
        unsigned short* Hbase = Hout + (size_t)er * hstride;
#pragma unroll
        for (int i = 0; i < 4; i++) {
#pragma unroll
            for (int r = 0; r < 4; r++) {
                int row = mrow + i * 16 + r;
                float g = gate[row * 8 + e];
                unsigned short* hr = Hbase + (size_t)row * D_H;
#pragma unroll
                for (int j = 0; j < 4; j++) {
                    int col = ncol + j * 16;
                    float v = fmaxf(acc[i][j][r] + bias[col], 0.f) * g;
                    hr[col] = f2bf(v);
                }
            }
        }
    } else {
#pragma unroll
        for (int i = 0; i < 4; i++) {
#pragma unroll
            for (int r = 0; r < 4; r++) {
                int row = mrow + i * 16 + r;
                float* orow = out + (size_t)row * D_OUT;
#pragma unroll
                for (int j = 0; j < 4; j++) {
                    int col = ncol + j * 16;
                    unsafeAtomicAdd(&orow[col], acc[i][j][r]);
                }
            }
        }
    }
}

extern "C" void kernel_launch(void* const* d_in, const int* in_sizes, int n_in,
                              void* d_out, int out_size, void* d_ws, size_t ws_size,
                              hipStream_t stream) {
    const float* x  = (const float*)d_in[0];
    const float* W1 = (const float*)d_in[1];
    const float* b1 = (const float*)d_in[2];
    const float* W2 = (const float*)d_in[3];
    const float* b2 = (const float*)d_in[4];
    const float* Wg = (const float*)d_in[5];
    const float* bg = (const float*)d_in[6];
    float* out = (float*)d_out;

    // workspace layout (~264 MiB; harness provides >= 411 MB per R2)
    char* p = (char*)d_ws;
    unsigned short* xb  = (unsigned short*)p; p += (size_t)N_TOK * D_IN * 2;        //   8 MiB
    unsigned short* W1T = (unsigned short*)p; p += (size_t)E_EXP * D_IN * D_H * 2;  //  64 MiB [e][h][k]
    unsigned short* W2T = (unsigned short*)p; p += (size_t)E_EXP * D_H * D_OUT * 2; //  64 MiB [e][o][h]
    float* gate         = (float*)p;          p += (size_t)N_TOK * E_EXP * 4;       // 128 KiB
    unsigned short* h   = (unsigned short*)p;                                       // 128 MiB (4 experts)

    const size_t hstride = (size_t)N_TOK * D_H;   // per-expert h' slice (32 MiB)

    cast_x_kernel<<<dim3(N_TOK * D_IN / 1024), 256, 0, stream>>>(x, xb);
    gate_kernel<<<dim3(N_TOK / 4), 256, 0, stream>>>(x, Wg, bg, gate);
    // W1 [e][1024][4096] -> W1T [e][4096][1024]
    transpose_cast<<<dim3(D_H / 32, D_IN / 32, E_EXP), 256, 0, stream>>>(W1, W1T, D_IN, D_H);
    // W2 [e][4096][1024] -> W2T [e][1024][4096]
    transpose_cast<<<dim3(D_OUT / 32, D_H / 32, E_EXP), 256, 0, stream>>>(W2, W2T, D_H, D_OUT);
    // out = sum_e gate*b2 (GEMM2 atomically accumulates on top)
    out_init_kernel<<<dim3(N_TOK * D_OUT / 1024), 256, 0, stream>>>(gate, b2, out);

    // two groups of 4 experts: h' (128 MiB) stays L3-resident between the pair
    for (int g = 0; g < 2; g++) {
        gemm_kernel<0><<<dim3(4096), 256, 0, stream>>>(
            xb, W1T, b1, gate, h, nullptr, g * 4, hstride);
        gemm_kernel<1><<<dim3(1024), 256, 0, stream>>>(
            h, W2T, nullptr, nullptr, nullptr, out, g * 4, hstride);
    }
}

// Round 4
// 935.013 us; speedup vs baseline: 1.7701x; 1.1965x over previous
//
#include <hip/hip_runtime.h>

#define E_EXP 8
#define D_IN 1024
#define D_H 4096
#define D_OUT 1024
#define N_TOK 4096

using f32x4  = __attribute__((ext_vector_type(4))) float;
using bf16x8 = __attribute__((ext_vector_type(8))) __bf16;
using us8    = __attribute__((ext_vector_type(8))) unsigned short;

typedef __attribute__((address_space(1))) void gvoid_t;
typedef __attribute__((address_space(3))) void lvoid_t;

// async global->LDS, 16B per lane; LDS dest is wave-uniform base + lane*16
__device__ __forceinline__ void async_load16(const void* g, void* l) {
    __builtin_amdgcn_global_load_lds((gvoid_t*)g, (lvoid_t*)l, 16, 0, 0);
}

__device__ __forceinline__ unsigned short f2bf(float f) {
    unsigned int x = __float_as_uint(f);
    x += 0x7fffu + ((x >> 16) & 1u);   // round-to-nearest-even
    return (unsigned short)(x >> 16);
}

// ---------------- cast x fp32 -> bf16 ----------------
__global__ __launch_bounds__(256) void cast_x_kernel(const float* __restrict__ in,
                                                     unsigned short* __restrict__ outp) {
    int i = blockIdx.x * 256 + threadIdx.x;
    float4 f0 = ((const float4*)in)[i * 2];
    float4 f1 = ((const float4*)in)[i * 2 + 1];
    us8 u;
    u[0] = f2bf(f0.x); u[1] = f2bf(f0.y); u[2] = f2bf(f0.z); u[3] = f2bf(f0.w);
    u[4] = f2bf(f1.x); u[5] = f2bf(f1.y); u[6] = f2bf(f1.z); u[7] = f2bf(f1.w);
    ((us8*)outp)[i] = u;
}

// ---------------- gate: softmax(x @ Wg + bg) over E=8, fp32 ----------------
__global__ __launch_bounds__(256) void gate_kernel(const float* __restrict__ x,
                                                   const float* __restrict__ Wg,
                                                   const float* __restrict__ bg,
                                                   float* __restrict__ gate) {
    int wave = threadIdx.x >> 6, lane = threadIdx.x & 63;
    int n = blockIdx.x * 4 + wave;
    int e = lane & 7, part = lane >> 3;                 // 8 experts x 8 K-parts
    const float* xr = x + (size_t)n * D_IN + part * (D_IN / 8);
    const float* wr = Wg + (size_t)part * (D_IN / 8) * E_EXP + e;
    float s = 0.f;
#pragma unroll 4
    for (int d = 0; d < D_IN / 8; d++) s += xr[d] * wr[d * E_EXP];
    s += __shfl_xor(s, 8);
    s += __shfl_xor(s, 16);
    s += __shfl_xor(s, 32);                              // full dot per expert
    s += bg[e];
    float m = s;
    m = fmaxf(m, __shfl_xor(m, 1));
    m = fmaxf(m, __shfl_xor(m, 2));
    m = fmaxf(m, __shfl_xor(m, 4));
    float ex = __expf(s - m);
    float sum = ex;
    sum += __shfl_xor(sum, 1);
    sum += __shfl_xor(sum, 2);
    sum += __shfl_xor(sum, 4);
    if (lane < 8) gate[n * 8 + lane] = ex / sum;
}

// ---------------- transpose+cast 64x64: in fp32 [z][R][C] -> out bf16 [z][C][R] ----------------
__global__ __launch_bounds__(256) void transpose_cast64(const float* __restrict__ in,
                                                        unsigned short* __restrict__ outp,
                                                        int R, int C) {
    in   += (size_t)blockIdx.z * R * C;
    outp += (size_t)blockIdx.z * R * C;
    __shared__ float tile[64][65];
    const int t = threadIdx.x;
    const int r0 = blockIdx.y * 64, c0 = blockIdx.x * 64;
    // load: 4 passes, float4 per thread
    {
        int r = t >> 4, cc = (t & 15) * 4;
#pragma unroll
        for (int p = 0; p < 4; p++) {
            float4 v = *(const float4*)(in + (size_t)(r0 + p * 16 + r) * C + c0 + cc);
            tile[p * 16 + r][cc]     = v.x;
            tile[p * 16 + r][cc + 1] = v.y;
            tile[p * 16 + r][cc + 2] = v.z;
            tile[p * 16 + r][cc + 3] = v.w;
        }
    }
    __syncthreads();
    // write: 2 passes, ushort8 per thread
    {
        int c = t >> 3, w = t & 7;
#pragma unroll
        for (int p = 0; p < 2; p++) {
            int cc = p * 32 + c;
            us8 v;
#pragma unroll
            for (int i = 0; i < 8; i++) v[i] = f2bf(tile[w * 8 + i][cc]);
            *(us8*)(outp + (size_t)(c0 + cc) * R + r0 + w * 8) = v;
        }
    }
}

// ---------------- out init: out[n][o] = sum_e gate[n,e]*b2[e,o] ----------------
__global__ __launch_bounds__(256) void out_init_kernel(const float* __restrict__ gate,
                                                       const float* __restrict__ b2,
                                                       float* __restrict__ out) {
    int i = blockIdx.x * 256 + threadIdx.x;          // one float4 of out
    int n = i / (D_OUT / 4), o4 = i % (D_OUT / 4);
    const float* g = gate + n * 8;
    float4 s = make_float4(0.f, 0.f, 0.f, 0.f);
#pragma unroll
    for (int e = 0; e < E_EXP; e++) {
        float4 b = ((const float4*)(b2 + (size_t)e * D_OUT))[o4];
        float ge = g[e];
        s.x += ge * b.x; s.y += ge * b.y; s.z += ge * b.z; s.w += ge * b.w;
    }
    ((float4*)out)[i] = s;
}

// ---------------- bf16 MFMA GEMM, 256x128 block tile, 128x64 wave tile, BK=64 ----------------
// LDS: As [256 rows][64 k], Bs [128 rows][64 k]; rows = 128 B = 8 chunks of 16 B.
// Swizzle: phys_chunk(row, c) = c ^ (row & 7)  -> ds_read_b128 conflict-free.
// MODE 0 (layer1): A=xb [N_TOK][D_IN], B=W1T[e][h][k], K=1024; writes
//                  h[er*hstride + row*D_H + col] = bf16(gate[row,e]*relu(acc + b1[e,col]))
// MODE 1 (layer2): A=h+er*hstride [N_TOK][D_H], B=W2T[e][o][h], K=4096;
//                  unsafeAtomicAdd(out[row*D_OUT + col], acc)
// 1-D grid, XCD-partitioned m-tiles, col-tile fastest, expert slowest.
template <int MODE>
__global__ __launch_bounds__(256, 2) void gemm_kernel(const unsigned short* __restrict__ Abase,
                                                      const unsigned short* __restrict__ Wbase,
                                                      const float* __restrict__ b1a,
                                                      const float* __restrict__ gate,
                                                      unsigned short* __restrict__ Hout,
                                                      float* __restrict__ out,
                                                      int e0, size_t hstride) {
    __shared__ __align__(16) unsigned short As[256 * 64];   // 32 KiB
    __shared__ __align__(16) unsigned short Bs[128 * 64];   // 16 KiB
    const int t = threadIdx.x;
    const int wave = t >> 6;
    const int lane = t & 63;
    const int quad = lane >> 4;
    const int l16 = lane & 15;

    const int lin = blockIdx.x;
    const int xcd = lin & 7;
    const int s = lin >> 3;
    int n_t, er, m_t;
    if (MODE == 0) {                 // 2048 blocks: s in [0,256)
        n_t = s & 31;                // 32 col-tiles of 128 (fastest: share A-tile)
        int em = s >> 5;             // [0,8)
        er = em >> 1;                // expert slowest
        m_t = (em & 1) + xcd * 2;    // 16 m-tiles of 256
    } else {                         // 512 blocks: s in [0,64)
        n_t = s & 7;                 // 8 col-tiles of 128
        int em = s >> 3;             // [0,8)
        er = em >> 1;
        m_t = (em & 1) + xcd * 2;
    }
    const int e = e0 + er;
    const int n0 = n_t * 128;
    const int m0 = m_t * 256;
    const int ld = (MODE == 0) ? D_IN : D_H;
    const int K  = (MODE == 0) ? D_IN : D_H;

    const unsigned short* A = Abase + (MODE == 1 ? (size_t)er * hstride : (size_t)0);
    const unsigned short* B = Wbase + (size_t)e * 4194304;   // 4M elems per expert slice

    // staging: A = 2048 phys chunks (t + j*256, j=0..7), B = 1024 (j=0..3).
    // phys p: row = p>>3, cph = p&7; global logical chunk c = cph ^ (row&7).
    const int r0 = t >> 3;                       // rows r0 + 32*j
    const int gk = ((t & 7) ^ (r0 & 7)) << 3;    // same for all j (32 % 8 == 0)
    const unsigned short* aP = A + (size_t)(m0 + r0) * ld + gk;
    const unsigned short* bP = B + (size_t)(n0 + r0) * ld + gk;

    const int wm = (wave & 1) * 128;
    const int wn = (wave >> 1) * 64;
    f32x4 acc[8][4] = {};

    for (int k = 0; k < K; k += 64) {
#pragma unroll
        for (int j = 0; j < 8; j++)
            async_load16(aP + k + (size_t)j * 32 * ld, &As[(j * 256 + wave * 64) * 8]);
#pragma unroll
        for (int j = 0; j < 4; j++)
            async_load16(bP + k + (size_t)j * 32 * ld, &Bs[(j * 256 + wave * 64) * 8]);
        __syncthreads();
#pragma unroll
        for (int half = 0; half < 2; half++) {
            bf16x8 af[8], bfr[4];
#pragma unroll
            for (int i = 0; i < 8; i++) {
                int row = wm + i * 16 + l16;
                af[i] = *reinterpret_cast<const bf16x8*>(
                    &As[row * 64 + (((half << 2) + quad) ^ (row & 7)) * 8]);
            }
#pragma unroll
            for (int j = 0; j < 4; j++) {
                int row = wn + j * 16 + l16;
                bfr[j] = *reinterpret_cast<const bf16x8*>(
                    &Bs[row * 64 + (((half << 2) + quad) ^ (row & 7)) * 8]);
            }
#pragma unroll
            for (int i = 0; i < 8; i++)
#pragma unroll
                for (int j = 0; j < 4; j++)
                    acc[i][j] = __builtin_amdgcn_mfma_f32_16x16x32_bf16(af[i], bfr[j], acc[i][j], 0, 0, 0);
        }
        __syncthreads();
    }

    // C/D layout: col = lane&15, row = quad*4 + reg   [verified m89/m91]
    const int mrow = m0 + wm + quad * 4;
    const int ncol = n0 + wn + l16;
    if (MODE == 0) {
        const float* bias = b1a + (size_t)e * D_H;
        unsigned short* Hbase = Hout + (size_t)er * hstride;
#pragma unroll
        for (int i = 0; i < 8; i++) {
#pragma unroll
            for (int r = 0; r < 4; r++) {
                int row = mrow + i * 16 + r;
                float g = gate[row * 8 + e];
                unsigned short* hr = Hbase + (size_t)row * D_H;
#pragma unroll
                for (int j = 0; j < 4; j++) {
                    int col = ncol + j * 16;
                    float v = fmaxf(acc[i][j][r] + bias[col], 0.f) * g;
                    hr[col] = f2bf(v);
                }
            }
        }
    } else {
#pragma unroll
        for (int i = 0; i < 8; i++) {
#pragma unroll
            for (int r = 0; r < 4; r++) {
                int row = mrow + i * 16 + r;
                float* orow = out + (size_t)row * D_OUT;
#pragma unroll
                for (int j = 0; j < 4; j++) {
                    int col = ncol + j * 16;
                    unsafeAtomicAdd(&orow[col], acc[i][j][r]);
                }
            }
        }
    }
}

extern "C" void kernel_launch(void* const* d_in, const int* in_sizes, int n_in,
                              void* d_out, int out_size, void* d_ws, size_t ws_size,
                              hipStream_t stream) {
    const float* x  = (const float*)d_in[0];
    const float* W1 = (const float*)d_in[1];
    const float* b1 = (const float*)d_in[2];
    const float* W2 = (const float*)d_in[3];
    const float* b2 = (const float*)d_in[4];
    const float* Wg = (const float*)d_in[5];
    const float* bg = (const float*)d_in[6];
    float* out = (float*)d_out;

    // workspace layout (~264 MiB)
    char* p = (char*)d_ws;
    unsigned short* xb  = (unsigned short*)p; p += (size_t)N_TOK * D_IN * 2;        //   8 MiB
    unsigned short* W1T = (unsigned short*)p; p += (size_t)E_EXP * D_IN * D_H * 2;  //  64 MiB [e][h][k]
    unsigned short* W2T = (unsigned short*)p; p += (size_t)E_EXP * D_H * D_OUT * 2; //  64 MiB [e][o][h]
    float* gate         = (float*)p;          p += (size_t)N_TOK * E_EXP * 4;       // 128 KiB
    unsigned short* h   = (unsigned short*)p;                                       // 128 MiB (4 experts)

    const size_t hstride = (size_t)N_TOK * D_H;   // per-expert h' slice (32 MiB)

    cast_x_kernel<<<dim3(N_TOK * D_IN / 2048), 256, 0, stream>>>(x, xb);
    gate_kernel<<<dim3(N_TOK / 4), 256, 0, stream>>>(x, Wg, bg, gate);
    // W1 [e][1024][4096] -> W1T [e][4096][1024]
    transpose_cast64<<<dim3(D_H / 64, D_IN / 64, E_EXP), 256, 0, stream>>>(W1, W1T, D_IN, D_H);
    // W2 [e][4096][1024] -> W2T [e][1024][4096]
    transpose_cast64<<<dim3(D_OUT / 64, D_H / 64, E_EXP), 256, 0, stream>>>(W2, W2T, D_H, D_OUT);
    // out = sum_e gate*b2 (GEMM2 atomically accumulates on top)
    out_init_kernel<<<dim3(N_TOK * D_OUT / 1024), 256, 0, stream>>>(gate, b2, out);

    // two groups of 4 experts: h' (128 MiB) stays L3-resident between the pair
    for (int g = 0; g < 2; g++) {
        gemm_kernel<0><<<dim3(2048), 256, 0, stream>>>(
            xb, W1T, b1, gate, h, nullptr, g * 4, hstride);
        gemm_kernel<1><<<dim3(512), 256, 0, stream>>>(
            h, W2T, nullptr, nullptr, nullptr, out, g * 4, hstride);
    }
}